// Round 9
// baseline (204.490 us; speedup 1.0000x reference)
//
#include <hip/hip_runtime.h>

// VQ-VAE quantize: z [32,64,64,64] NCHW fp32, codebook [512,64] fp32.
// out = quantized (8388608 fp32, NCHW) ++ loss scalar. N=131072, D=64, K=512.
//
// R9 (from R8's 109us/171us): (1) prep fused into vq_main (R8's vq_prep ran
// 512 threads on 2 CUs ~ 40us; now each block bf16-splits its own cb tiles
// during staging, cn per-block R5-style); (2) fallback via __ballot work-list
// (R8 scanned 128 rows serially ~ 7us/block-round); (3) cb tiles 64-code,
// double-buffered LDS + register prefetch so global latency hides under MFMA.
// Rank = cn - 2*dot via 3-pass hi/lo bf16 MFMA; gap<=TAU rows -> np-bit-exact
// block rescan (R5-validated chain). absmax 0.0 lineage R8.

typedef __bf16 bf8 __attribute__((ext_vector_type(8)));
typedef float  f4  __attribute__((ext_vector_type(4)));

#define Dz    64
#define HWz   4096
#define Nz    131072
#define QSIZE ((size_t)Nz * Dz)
#define PSTR  132        // zT row stride (floats)
#define CROW  74         // split-cb row stride (ushorts) -> odd dword stride
#define BUFU  9472       // ushorts per cb buffer (hi+lo): 2*64*74
#define LOOFF 4736       // lo-plane offset (ushorts) = 64*74
#define TAU   4e-3f

#define MFMA(A, B, C) __builtin_amdgcn_mfma_f32_16x16x32_bf16(A, B, C, 0, 0, 0)

#define DECL8(P) float P##0, P##1, P##2, P##3, P##4, P##5, P##6, P##7;
#define DECI8(P) int   P##0, P##1, P##2, P##3, P##4, P##5, P##6, P##7;

// best/second update: second computed from OLD best (order matters).
#define UPDR(ACCE, B, K, S)                                            \
    {   const float vv = __builtin_fmaf(ACCE, -2.0f, cnv);             \
        S = fminf(S, fmaxf(B, vv));                                    \
        K = (vv < B) ? kcand : K;                                      \
        B = fminf(B, vv); }

#define REDR(B, K, S)                                                  \
    _Pragma("unroll")                                                  \
    for (int mm = 1; mm < 16; mm <<= 1) {                              \
        const float ob = __shfl_xor(B, mm, 64);                        \
        const int   ok = __shfl_xor(K, mm, 64);                        \
        const float os = __shfl_xor(S, mm, 64);                        \
        S = fminf(fminf(S, os), fmaxf(B, ob));                         \
        K = (ob < B) ? ok : K;                                         \
        B = fminf(B, ob); }

#define SPL(V, HV, LV, J)                                              \
    { const __bf16 hh = (__bf16)(V); HV[J] = hh;                       \
      LV[J] = (__bf16)((V) - (float)hh); }

// prefetch one 64-code tile's 16 floats for this thread into r0..r3
#define PREFETCH(KT)                                                   \
    {   const float4* srcp = (const float4*)                           \
            (cb + ((size_t)(KT) * 64 + cstage) * 64 + dstage * 16);    \
        r0 = srcp[0]; r1 = srcp[1]; r2 = srcp[2]; r3 = srcp[3]; }

#define CONVERT_WRITE(KT)                                              \
    {   bf8 h0, l0v, h1, l1v;                                          \
        SPL(r0.x,h0,l0v,0) SPL(r0.y,h0,l0v,1) SPL(r0.z,h0,l0v,2)       \
        SPL(r0.w,h0,l0v,3) SPL(r1.x,h0,l0v,4) SPL(r1.y,h0,l0v,5)       \
        SPL(r1.z,h0,l0v,6) SPL(r1.w,h0,l0v,7)                          \
        SPL(r2.x,h1,l1v,0) SPL(r2.y,h1,l1v,1) SPL(r2.z,h1,l1v,2)       \
        SPL(r2.w,h1,l1v,3) SPL(r3.x,h1,l1v,4) SPL(r3.y,h1,l1v,5)       \
        SPL(r3.z,h1,l1v,6) SPL(r3.w,h1,l1v,7)                          \
        unsigned short* basep = cbS + ((KT) & 1) * BUFU                \
                              + cstage * CROW + dstage * 16;           \
        *(bf8*)(basep)             = h0;  *(bf8*)(basep + 8)         = h1;  \
        *(bf8*)(basep + LOOFF)     = l0v; *(bf8*)(basep + LOOFF + 8) = l1v; }

__global__ __launch_bounds__(256, 2) void vq_main(
    const float* __restrict__ z, const float* __restrict__ cb,
    float* __restrict__ out, float* __restrict__ loss_accum,
    unsigned int* __restrict__ done_counter) {
    __shared__ float  zT[Dz * PSTR];            // 33792 B
    __shared__ unsigned short cbS[2 * BUFU];    // 37888 B (hi+lo per buffer)
    __shared__ float  cn_s[512];
    __shared__ int    idx_s[128];
    __shared__ unsigned long long flagm[2];
    __shared__ float  wredD[4];
    __shared__ int    wredK[4];
    __shared__ float  wsum[4];

    const int t  = threadIdx.x;
    const int w  = t >> 6;
    const int l  = t & 63;
    const int q  = l >> 4;
    const int m16 = l & 15;
    const int cstage = t >> 2;      // code within 64-code tile
    const int dstage = t & 3;       // 16-d chunk
    const int n0g = blockIdx.x * 128;
    const int b   = n0g >> 12;
    const int s0  = n0g & 4095;
    const float* zB = z + (size_t)b * (Dz * HWz);

    float4 r0, r1, r2, r3;

    // ---- stage zT (2048 f4, flat) + cn (2 codes/thread) + cb tile 0.
    PREFETCH(0)
#pragma unroll
    for (int i = 0; i < 8; ++i) {
        const int flat = t + 256 * i;
        const int d = flat >> 5, c4 = flat & 31;
        float4 f = *(const float4*)(zB + (size_t)d * HWz + s0 + 4 * c4);
        *(float4*)(zT + d * PSTR + 4 * c4) = f;
    }
    {   // numpy pairwise-8 cnorm, 2 codes per thread (exact; contract off)
#pragma clang fp contract(off)
#pragma unroll
        for (int h = 0; h < 2; ++h) {
            const int k = t + 256 * h;
            const float4* row = (const float4*)(cb + (size_t)k * 64);
            float c0, c1, c2, c3, c4, c5, c6, c7;
            {
                float4 f0 = row[0], f1 = row[1];
                c0 = f0.x * f0.x; c1 = f0.y * f0.y; c2 = f0.z * f0.z; c3 = f0.w * f0.w;
                c4 = f1.x * f1.x; c5 = f1.y * f1.y; c6 = f1.z * f1.z; c7 = f1.w * f1.w;
            }
#pragma unroll
            for (int m = 1; m < 8; ++m) {
                float4 f0 = row[2 * m], f1 = row[2 * m + 1];
                c0 = c0 + f0.x * f0.x; c1 = c1 + f0.y * f0.y;
                c2 = c2 + f0.z * f0.z; c3 = c3 + f0.w * f0.w;
                c4 = c4 + f1.x * f1.x; c5 = c5 + f1.y * f1.y;
                c6 = c6 + f1.z * f1.z; c7 = c7 + f1.w * f1.w;
            }
            cn_s[k] = ((c0 + c1) + (c2 + c3)) + ((c4 + c5) + (c6 + c7));
        }
    }
    CONVERT_WRITE(0)
    __syncthreads();

    // ---- build A fragments (both 16-pos subtiles, hi+lo, 2 k-chunks).
    bf8 ah00, ah01, al00, al01, ah10, ah11, al10, al11;
    {
        const int pA = 32 * w + m16, pB = pA + 16;
#define BUILDA(AH, AL, P, KC)                                          \
        _Pragma("unroll")                                              \
        for (int j = 0; j < 8; ++j) {                                  \
            const float v = zT[((KC) * 32 + q * 8 + j) * PSTR + (P)];  \
            const __bf16 hh = (__bf16)v;                               \
            AH[j] = hh;                                                \
            AL[j] = (__bf16)(v - (float)hh);                           \
        }
        BUILDA(ah00, al00, pA, 0) BUILDA(ah01, al01, pA, 1)
        BUILDA(ah10, al10, pB, 0) BUILDA(ah11, al11, pB, 1)
#undef BUILDA
    }

    // ---- K loop: 8 tiles x 64 codes, double-buffered cbS + reg prefetch.
    const float INF = __builtin_inff();
    DECL8(bd) DECI8(bk) DECL8(sd)
    bd0=INF;bd1=INF;bd2=INF;bd3=INF;bd4=INF;bd5=INF;bd6=INF;bd7=INF;
    sd0=INF;sd1=INF;sd2=INF;sd3=INF;sd4=INF;sd5=INF;sd6=INF;sd7=INF;
    bk0=0;bk1=0;bk2=0;bk3=0;bk4=0;bk5=0;bk6=0;bk7=0;

#pragma unroll 1
    for (int kt = 0; kt < 8; ++kt) {
        if (kt < 7) PREFETCH(kt + 1)
        const unsigned short* hib = cbS + (kt & 1) * BUFU;
        const int k0g = kt * 64;
#pragma unroll
        for (int n0 = 0; n0 < 64; n0 += 16) {
            const int nlane = n0 + m16;
            const int hoff = nlane * CROW + q * 8;
            const bf8 bh0 = *(const bf8*)(hib + hoff);
            const bf8 bh1 = *(const bf8*)(hib + hoff + 32);
            const bf8 bl0 = *(const bf8*)(hib + hoff + LOOFF);
            const bf8 bl1 = *(const bf8*)(hib + hoff + LOOFF + 32);
            f4 acc0 = {0.f, 0.f, 0.f, 0.f}, acc1 = {0.f, 0.f, 0.f, 0.f};
            acc0 = MFMA(ah00, bh0, acc0); acc0 = MFMA(ah01, bh1, acc0);
            acc1 = MFMA(ah10, bh0, acc1); acc1 = MFMA(ah11, bh1, acc1);
            acc0 = MFMA(al00, bh0, acc0); acc0 = MFMA(al01, bh1, acc0);
            acc1 = MFMA(al10, bh0, acc1); acc1 = MFMA(al11, bh1, acc1);
            acc0 = MFMA(ah00, bl0, acc0); acc0 = MFMA(ah01, bl1, acc0);
            acc1 = MFMA(ah10, bl0, acc1); acc1 = MFMA(ah11, bl1, acc1);
            const float cnv = cn_s[k0g + nlane];
            const int kcand = k0g + nlane;
            UPDR(acc0[0], bd0, bk0, sd0) UPDR(acc0[1], bd1, bk1, sd1)
            UPDR(acc0[2], bd2, bk2, sd2) UPDR(acc0[3], bd3, bk3, sd3)
            UPDR(acc1[0], bd4, bk4, sd4) UPDR(acc1[1], bd5, bk5, sd5)
            UPDR(acc1[2], bd6, bk6, sd6) UPDR(acc1[3], bd7, bk7, sd7)
        }
        if (kt < 7) CONVERT_WRITE(kt + 1)
        __syncthreads();
    }

    // ---- cross-lane reduce + flag near-ties.
    REDR(bd0, bk0, sd0) REDR(bd1, bk1, sd1) REDR(bd2, bk2, sd2) REDR(bd3, bk3, sd3)
    REDR(bd4, bk4, sd4) REDR(bd5, bk5, sd5) REDR(bd6, bk6, sd6) REDR(bd7, bk7, sd7)
    if (m16 == 0) {
        const int base = 32 * w + 4 * q;
        idx_s[base + 0]      = (sd0 - bd0 <= TAU) ? -1 : bk0;
        idx_s[base + 1]      = (sd1 - bd1 <= TAU) ? -1 : bk1;
        idx_s[base + 2]      = (sd2 - bd2 <= TAU) ? -1 : bk2;
        idx_s[base + 3]      = (sd3 - bd3 <= TAU) ? -1 : bk3;
        idx_s[base + 16 + 0] = (sd4 - bd4 <= TAU) ? -1 : bk4;
        idx_s[base + 16 + 1] = (sd5 - bd5 <= TAU) ? -1 : bk5;
        idx_s[base + 16 + 2] = (sd6 - bd6 <= TAU) ? -1 : bk6;
        idx_s[base + 16 + 3] = (sd7 - bd7 <= TAU) ? -1 : bk7;
    }
    __syncthreads();

    // ---- ballot work-list of flagged rows (waves 0,1 cover rows 0..127).
    if (t < 128) {
        unsigned long long mflag = __ballot(idx_s[t] < 0);
        if (l == 0) flagm[w] = mflag;
    }
    __syncthreads();

    // ---- fallback: np-bit-exact rescan for flagged rows only.
#pragma unroll 1
    for (int half = 0; half < 2; ++half) {
        unsigned long long m = flagm[half];      // block-uniform
        while (m) {
            const int row = (half << 6) + __builtin_ctzll(m);
            m &= m - 1;
            float zn;
            {   // np pairwise-8 znorm (broadcast LDS reads)
#pragma clang fp contract(off)
                float c0, c1, c2, c3, c4, c5, c6, c7;
                c0 = zT[0*PSTR+row]*zT[0*PSTR+row]; c1 = zT[1*PSTR+row]*zT[1*PSTR+row];
                c2 = zT[2*PSTR+row]*zT[2*PSTR+row]; c3 = zT[3*PSTR+row]*zT[3*PSTR+row];
                c4 = zT[4*PSTR+row]*zT[4*PSTR+row]; c5 = zT[5*PSTR+row]*zT[5*PSTR+row];
                c6 = zT[6*PSTR+row]*zT[6*PSTR+row]; c7 = zT[7*PSTR+row]*zT[7*PSTR+row];
#pragma unroll
                for (int mi = 1; mi < 8; ++mi) {
                    float v0 = zT[(8*mi+0)*PSTR+row], v1 = zT[(8*mi+1)*PSTR+row];
                    float v2 = zT[(8*mi+2)*PSTR+row], v3 = zT[(8*mi+3)*PSTR+row];
                    float v4 = zT[(8*mi+4)*PSTR+row], v5 = zT[(8*mi+5)*PSTR+row];
                    float v6 = zT[(8*mi+6)*PSTR+row], v7 = zT[(8*mi+7)*PSTR+row];
                    c0 = c0 + v0*v0; c1 = c1 + v1*v1; c2 = c2 + v2*v2; c3 = c3 + v3*v3;
                    c4 = c4 + v4*v4; c5 = c5 + v5*v5; c6 = c6 + v6*v6; c7 = c7 + v7*v7;
                }
                zn = ((c0 + c1) + (c2 + c3)) + ((c4 + c5) + (c6 + c7));
            }
            float fbd; int fbk;
            {   // codes t and t+256, exact sequential-d chain (R5-validated)
                float dd0, dd1;
#pragma unroll
                for (int h = 0; h < 2; ++h) {
                    const int k = t + 256 * h;
                    const float4* C = (const float4*)(cb + (size_t)k * 64);
                    float a = 0.f;
#pragma unroll
                    for (int i = 0; i < 16; ++i) {
                        const float4 c4v = C[i];
                        a = __builtin_fmaf(zT[(4*i+0)*PSTR+row], c4v.x, a);
                        a = __builtin_fmaf(zT[(4*i+1)*PSTR+row], c4v.y, a);
                        a = __builtin_fmaf(zT[(4*i+2)*PSTR+row], c4v.z, a);
                        a = __builtin_fmaf(zT[(4*i+3)*PSTR+row], c4v.w, a);
                    }
                    const float dv = (zn - 2.0f * a) + cn_s[k];
                    if (h == 0) dd0 = dv; else dd1 = dv;
                }
                fbd = dd0; fbk = t;
                if (dd1 < fbd) { fbd = dd1; fbk = t + 256; }
            }
#pragma unroll
            for (int mm = 1; mm < 64; mm <<= 1) {
                const float ob = __shfl_xor(fbd, mm, 64);
                const int   ok = __shfl_xor(fbk, mm, 64);
                if (ob < fbd || (ob == fbd && ok < fbk)) { fbd = ob; fbk = ok; }
            }
            if (l == 0) { wredD[w] = fbd; wredK[w] = fbk; }
            __syncthreads();
            if (t == 0) {
                float fb = wredD[0]; int fk = wredK[0];
#pragma unroll
                for (int i = 1; i < 4; ++i) {
                    if (wredD[i] < fb || (wredD[i] == fb && wredK[i] < fk)) {
                        fb = wredD[i]; fk = wredK[i];
                    }
                }
                idx_s[row] = fk;
            }
            __syncthreads();
        }
    }

    // ---- epilogue: gather code, write q_st (NCHW coalesced), loss.
    const int p  = t & 127;
    const int d0 = (t >> 7) * 32;
    const int myidx = idx_s[p];
    const float* qrow = cb + (size_t)myidx * 64 + d0;
    float* oB = out + (size_t)b * (Dz * HWz) + s0 + p;
    float lsum = 0.f;
#pragma unroll
    for (int j = 0; j < 8; ++j) {
        const int d = d0 + 4 * j;
        const float4 q4 = *(const float4*)(qrow + 4 * j);
        const float y0 = zT[(d + 0) * PSTR + p];
        const float y1 = zT[(d + 1) * PSTR + p];
        const float y2 = zT[(d + 2) * PSTR + p];
        const float y3 = zT[(d + 3) * PSTR + p];
        const float e0 = y0 - q4.x, e1 = y1 - q4.y;
        const float e2 = y2 - q4.z, e3 = y3 - q4.w;
        lsum += e0 * e0; lsum += e1 * e1; lsum += e2 * e2; lsum += e3 * e3;
        oB[(size_t)(d + 0) * HWz] = y0 + (q4.x - y0);
        oB[(size_t)(d + 1) * HWz] = y1 + (q4.y - y1);
        oB[(size_t)(d + 2) * HWz] = y2 + (q4.z - y2);
        oB[(size_t)(d + 3) * HWz] = y3 + (q4.w - y3);
    }
#pragma unroll
    for (int off = 32; off > 0; off >>= 1) lsum += __shfl_down(lsum, off, 64);
    if (l == 0) wsum[w] = lsum;
    __syncthreads();
    if (t == 0) {
        float tot = (wsum[0] + wsum[1]) + (wsum[2] + wsum[3]);
        atomicAdd(loss_accum, tot);
        __threadfence();
        unsigned int ticket = atomicAdd(done_counter, 1u);
        if (ticket == gridDim.x - 1) {
            __threadfence();
            float total = atomicAdd(loss_accum, 0.0f);
            float X = total / (float)QSIZE;
            out[QSIZE] = X + 0.25f * X;
        }
    }
}

extern "C" void kernel_launch(void* const* d_in, const int* in_sizes, int n_in,
                              void* d_out, int out_size, void* d_ws, size_t ws_size,
                              hipStream_t stream) {
    const float* z  = (const float*)d_in[0];
    const float* cb = (const float*)d_in[1];
    float* out = (float*)d_out;
    float* lossp = (float*)d_ws;
    unsigned int* donep = (unsigned int*)(lossp + 1);
    hipMemsetAsync(d_ws, 0, 8, stream);
    vq_main<<<Nz / 128, 256, 0, stream>>>(z, cb, out, lossp, donep);
}

// Round 10
// 183.640 us; speedup vs baseline: 1.1135x; 1.1135x over previous
//
#include <hip/hip_runtime.h>

// VQ-VAE quantize: z [32,64,64,64] NCHW fp32, codebook [512,64] fp32.
// out = quantized (8388608 fp32, NCHW) ++ loss scalar. N=131072, D=64, K=512.
//
// R10: parallel prep (32x256, ushort4 stores, CROW=72 aligned layout; fuses
// the ws zeroing -> 2 dispatches) + R8-style MFMA main with single-buffer
// 64-code tiles + register prefetch (dbuf effect, half the LDS) + PSTR=128
// -> ~53.8 KB LDS -> 3 blocks/CU. Ballot fallback from R9. Rank = cn - 2*dot
// via 3-pass hi/lo bf16 MFMA; gap<=TAU rows -> np-bit-exact block rescan.
// absmax 0.0 lineage R8/R9.

typedef __bf16 bf8 __attribute__((ext_vector_type(8)));
typedef float  f4  __attribute__((ext_vector_type(4)));

#define Dz     64
#define HWz    4096
#define Nz     131072
#define QSIZE  ((size_t)Nz * Dz)
#define PSTR   128       // zT row stride (floats); all zT access is row-contig or bcast
#define CROW   72        // split-cb row stride (ushorts) = 144B (16B-aligned rows)
#define BUFU   9216      // ushorts per 64-code tile (hi+lo planes)
#define LOOFF  4608      // lo-plane offset (ushorts) = 64*72
#define TILE_F4 1152     // BUFU*2B/16B
#define TAU    4e-3f

#define MFMA(A, B, C) __builtin_amdgcn_mfma_f32_16x16x32_bf16(A, B, C, 0, 0, 0)

#define DECL8(P) float P##0, P##1, P##2, P##3, P##4, P##5, P##6, P##7;
#define DECI8(P) int   P##0, P##1, P##2, P##3, P##4, P##5, P##6, P##7;

// best/second update: second computed from OLD best (order matters).
#define UPDR(ACCE, B, K, S)                                            \
    {   const float vv = __builtin_fmaf(ACCE, -2.0f, cnv);             \
        S = fminf(S, fmaxf(B, vv));                                    \
        K = (vv < B) ? kcand : K;                                      \
        B = fminf(B, vv); }

#define REDR(B, K, S)                                                  \
    _Pragma("unroll")                                                  \
    for (int mm = 1; mm < 16; mm <<= 1) {                              \
        const float ob = __shfl_xor(B, mm, 64);                        \
        const int   ok = __shfl_xor(K, mm, 64);                        \
        const float os = __shfl_xor(S, mm, 64);                        \
        S = fminf(fminf(S, os), fmaxf(B, ob));                         \
        K = (ob < B) ? ok : K;                                         \
        B = fminf(B, ob); }

// ---------------- prep: split cb -> bf16 hi/lo tiles + exact cnorm ----------
__global__ __launch_bounds__(256) void vq_prep(
    const float* __restrict__ cb, unsigned short* __restrict__ cbws,
    float* __restrict__ cnws, float* __restrict__ lossp,
    unsigned int* __restrict__ donep) {
    const int f = blockIdx.x * 256 + threadIdx.x;   // 0..8191
    const int k = f >> 4, c = f & 15;
    if (f == 0) { lossp[0] = 0.0f; donep[0] = 0u; }
    const float4 v = ((const float4*)cb)[(size_t)k * 16 + c];
    unsigned short h0, h1, h2, h3, l0, l1, l2, l3;
#define S1(X, H, L)                                                    \
    { const __bf16 hh = (__bf16)(X);                                   \
      H = __builtin_bit_cast(unsigned short, hh);                      \
      L = __builtin_bit_cast(unsigned short, (__bf16)((X) - (float)hh)); }
    S1(v.x, h0, l0) S1(v.y, h1, l1) S1(v.z, h2, l2) S1(v.w, h3, l3)
#undef S1
    const int kt = k >> 6, kc = k & 63;
    unsigned short* base = cbws + (size_t)kt * BUFU + kc * CROW + c * 4;
    *(ushort4*)base = make_ushort4(h0, h1, h2, h3);           // 8B-aligned
    *(ushort4*)(base + LOOFF) = make_ushort4(l0, l1, l2, l3); // 8B-aligned
    if (c == 0) {  // numpy pairwise-8 cnorm (squares round before add)
#pragma clang fp contract(off)
        const float4* row = (const float4*)(cb + (size_t)k * 64);
        float r0, r1, r2, r3, r4, r5, r6, r7;
        {
            float4 f0 = row[0], f1 = row[1];
            r0 = f0.x * f0.x; r1 = f0.y * f0.y; r2 = f0.z * f0.z; r3 = f0.w * f0.w;
            r4 = f1.x * f1.x; r5 = f1.y * f1.y; r6 = f1.z * f1.z; r7 = f1.w * f1.w;
        }
#pragma unroll
        for (int m = 1; m < 8; ++m) {
            float4 f0 = row[2 * m], f1 = row[2 * m + 1];
            r0 = r0 + f0.x * f0.x; r1 = r1 + f0.y * f0.y;
            r2 = r2 + f0.z * f0.z; r3 = r3 + f0.w * f0.w;
            r4 = r4 + f1.x * f1.x; r5 = r5 + f1.y * f1.y;
            r6 = r6 + f1.z * f1.z; r7 = r7 + f1.w * f1.w;
        }
        cnws[k] = ((r0 + r1) + (r2 + r3)) + ((r4 + r5) + (r6 + r7));
    }
}

// ---------------- main ----------------
#define PREFETCH(KT)                                                   \
    {   const f4* srcp = (const f4*)(cbws + (size_t)(KT) * BUFU);      \
        p0 = srcp[t]; p1 = srcp[t + 256]; p2 = srcp[t + 512];          \
        p3 = srcp[t + 768];                                            \
        if (t < TILE_F4 - 1024) p4 = srcp[t + 1024]; }

#define WRITE_TILE()                                                   \
    {   f4* dstp = (f4*)cbS;                                           \
        dstp[t] = p0; dstp[t + 256] = p1; dstp[t + 512] = p2;          \
        dstp[t + 768] = p3;                                            \
        if (t < TILE_F4 - 1024) dstp[t + 1024] = p4; }

__global__ __launch_bounds__(256, 3) void vq_main(
    const float* __restrict__ z, const float* __restrict__ cb,
    const unsigned short* __restrict__ cbws, const float* __restrict__ cnws,
    float* __restrict__ out, float* __restrict__ loss_accum,
    unsigned int* __restrict__ done_counter) {
    __shared__ alignas(16) float  zT[Dz * PSTR];        // 32768 B
    __shared__ alignas(16) unsigned short cbS[BUFU];    // 18432 B
    __shared__ alignas(16) float  cn_s[512];            // 2048 B
    __shared__ int    idx_s[128];
    __shared__ unsigned long long flagm[2];
    __shared__ float  wredD[4];
    __shared__ int    wredK[4];
    __shared__ float  wsum[4];

    const int t  = threadIdx.x;
    const int w  = t >> 6;
    const int l  = t & 63;
    const int q  = l >> 4;
    const int m16 = l & 15;
    const int n0g = blockIdx.x * 128;
    const int b   = n0g >> 12;
    const int s0  = n0g & 4095;
    const float* zB = z + (size_t)b * (Dz * HWz);

    f4 p0, p1, p2, p3, p4;
    PREFETCH(0)

    // ---- stage zT (2048 f4, flat) + cn_s.
#pragma unroll
    for (int i = 0; i < 8; ++i) {
        const int flat = t + 256 * i;
        const int d = flat >> 5, c4 = flat & 31;
        float4 f = *(const float4*)(zB + (size_t)d * HWz + s0 + 4 * c4);
        *(float4*)(zT + d * PSTR + 4 * c4) = f;
    }
    if (t < 128) ((f4*)cn_s)[t] = ((const f4*)cnws)[t];
    __syncthreads();

    // ---- build A fragments (both 16-pos subtiles, hi+lo, 2 k-chunks).
    bf8 ah00, ah01, al00, al01, ah10, ah11, al10, al11;
    {
        const int pA = 32 * w + m16, pB = pA + 16;
#define BUILDA(AH, AL, P, KC)                                          \
        _Pragma("unroll")                                              \
        for (int j = 0; j < 8; ++j) {                                  \
            const float v = zT[((KC) * 32 + q * 8 + j) * PSTR + (P)];  \
            const __bf16 hh = (__bf16)v;                               \
            AH[j] = hh;                                                \
            AL[j] = (__bf16)(v - (float)hh);                           \
        }
        BUILDA(ah00, al00, pA, 0) BUILDA(ah01, al01, pA, 1)
        BUILDA(ah10, al10, pB, 0) BUILDA(ah11, al11, pB, 1)
#undef BUILDA
    }

    // ---- K loop: 8 tiles x 64 codes, single LDS buffer + register prefetch.
    const float INF = __builtin_inff();
    DECL8(bd) DECI8(bk) DECL8(sd)
    bd0=INF;bd1=INF;bd2=INF;bd3=INF;bd4=INF;bd5=INF;bd6=INF;bd7=INF;
    sd0=INF;sd1=INF;sd2=INF;sd3=INF;sd4=INF;sd5=INF;sd6=INF;sd7=INF;
    bk0=0;bk1=0;bk2=0;bk3=0;bk4=0;bk5=0;bk6=0;bk7=0;

#pragma unroll 1
    for (int kt = 0; kt < 8; ++kt) {
        if (kt > 0) __syncthreads();   // previous tile's reads complete
        WRITE_TILE()
        __syncthreads();
        if (kt < 7) PREFETCH(kt + 1)   // in flight across this tile's MFMA
        const int k0g = kt * 64;
#pragma unroll
        for (int n0 = 0; n0 < 64; n0 += 16) {
            const int nlane = n0 + m16;
            const int hoff = nlane * CROW + q * 8;
            const bf8 bh0 = *(const bf8*)(cbS + hoff);
            const bf8 bh1 = *(const bf8*)(cbS + hoff + 32);
            const bf8 bl0 = *(const bf8*)(cbS + hoff + LOOFF);
            const bf8 bl1 = *(const bf8*)(cbS + hoff + LOOFF + 32);
            f4 acc0 = {0.f, 0.f, 0.f, 0.f}, acc1 = {0.f, 0.f, 0.f, 0.f};
            acc0 = MFMA(ah00, bh0, acc0); acc0 = MFMA(ah01, bh1, acc0);
            acc1 = MFMA(ah10, bh0, acc1); acc1 = MFMA(ah11, bh1, acc1);
            acc0 = MFMA(al00, bh0, acc0); acc0 = MFMA(al01, bh1, acc0);
            acc1 = MFMA(al10, bh0, acc1); acc1 = MFMA(al11, bh1, acc1);
            acc0 = MFMA(ah00, bl0, acc0); acc0 = MFMA(ah01, bl1, acc0);
            acc1 = MFMA(ah10, bl0, acc1); acc1 = MFMA(ah11, bl1, acc1);
            const float cnv = cn_s[k0g + nlane];
            const int kcand = k0g + nlane;
            UPDR(acc0[0], bd0, bk0, sd0) UPDR(acc0[1], bd1, bk1, sd1)
            UPDR(acc0[2], bd2, bk2, sd2) UPDR(acc0[3], bd3, bk3, sd3)
            UPDR(acc1[0], bd4, bk4, sd4) UPDR(acc1[1], bd5, bk5, sd5)
            UPDR(acc1[2], bd6, bk6, sd6) UPDR(acc1[3], bd7, bk7, sd7)
        }
    }

    // ---- cross-lane reduce + flag near-ties.
    REDR(bd0, bk0, sd0) REDR(bd1, bk1, sd1) REDR(bd2, bk2, sd2) REDR(bd3, bk3, sd3)
    REDR(bd4, bk4, sd4) REDR(bd5, bk5, sd5) REDR(bd6, bk6, sd6) REDR(bd7, bk7, sd7)
    if (m16 == 0) {
        const int base = 32 * w + 4 * q;
        idx_s[base + 0]      = (sd0 - bd0 <= TAU) ? -1 : bk0;
        idx_s[base + 1]      = (sd1 - bd1 <= TAU) ? -1 : bk1;
        idx_s[base + 2]      = (sd2 - bd2 <= TAU) ? -1 : bk2;
        idx_s[base + 3]      = (sd3 - bd3 <= TAU) ? -1 : bk3;
        idx_s[base + 16 + 0] = (sd4 - bd4 <= TAU) ? -1 : bk4;
        idx_s[base + 16 + 1] = (sd5 - bd5 <= TAU) ? -1 : bk5;
        idx_s[base + 16 + 2] = (sd6 - bd6 <= TAU) ? -1 : bk6;
        idx_s[base + 16 + 3] = (sd7 - bd7 <= TAU) ? -1 : bk7;
    }
    __syncthreads();

    // ---- ballot work-list of flagged rows.
    if (t < 128) {
        unsigned long long mflag = __ballot(idx_s[t] < 0);
        if (l == 0) flagm[w] = mflag;
    }
    __syncthreads();

    // ---- fallback: np-bit-exact rescan for flagged rows only.
#pragma unroll 1
    for (int half = 0; half < 2; ++half) {
        unsigned long long m = flagm[half];      // block-uniform
        while (m) {
            const int row = (half << 6) + __builtin_ctzll(m);
            m &= m - 1;
            float zn;
            {   // np pairwise-8 znorm (broadcast LDS reads)
#pragma clang fp contract(off)
                float c0, c1, c2, c3, c4, c5, c6, c7;
                c0 = zT[0*PSTR+row]*zT[0*PSTR+row]; c1 = zT[1*PSTR+row]*zT[1*PSTR+row];
                c2 = zT[2*PSTR+row]*zT[2*PSTR+row]; c3 = zT[3*PSTR+row]*zT[3*PSTR+row];
                c4 = zT[4*PSTR+row]*zT[4*PSTR+row]; c5 = zT[5*PSTR+row]*zT[5*PSTR+row];
                c6 = zT[6*PSTR+row]*zT[6*PSTR+row]; c7 = zT[7*PSTR+row]*zT[7*PSTR+row];
#pragma unroll
                for (int mi = 1; mi < 8; ++mi) {
                    float v0 = zT[(8*mi+0)*PSTR+row], v1 = zT[(8*mi+1)*PSTR+row];
                    float v2 = zT[(8*mi+2)*PSTR+row], v3 = zT[(8*mi+3)*PSTR+row];
                    float v4 = zT[(8*mi+4)*PSTR+row], v5 = zT[(8*mi+5)*PSTR+row];
                    float v6 = zT[(8*mi+6)*PSTR+row], v7 = zT[(8*mi+7)*PSTR+row];
                    c0 = c0 + v0*v0; c1 = c1 + v1*v1; c2 = c2 + v2*v2; c3 = c3 + v3*v3;
                    c4 = c4 + v4*v4; c5 = c5 + v5*v5; c6 = c6 + v6*v6; c7 = c7 + v7*v7;
                }
                zn = ((c0 + c1) + (c2 + c3)) + ((c4 + c5) + (c6 + c7));
            }
            float fbd; int fbk;
            {   // codes t and t+256, exact sequential-d chain (R5-validated)
                float dd0, dd1;
#pragma unroll
                for (int h = 0; h < 2; ++h) {
                    const int k = t + 256 * h;
                    const float4* C = (const float4*)(cb + (size_t)k * 64);
                    float a = 0.f;
#pragma unroll
                    for (int i = 0; i < 16; ++i) {
                        const float4 c4v = C[i];
                        a = __builtin_fmaf(zT[(4*i+0)*PSTR+row], c4v.x, a);
                        a = __builtin_fmaf(zT[(4*i+1)*PSTR+row], c4v.y, a);
                        a = __builtin_fmaf(zT[(4*i+2)*PSTR+row], c4v.z, a);
                        a = __builtin_fmaf(zT[(4*i+3)*PSTR+row], c4v.w, a);
                    }
                    const float dv = (zn - 2.0f * a) + cn_s[k];
                    if (h == 0) dd0 = dv; else dd1 = dv;
                }
                fbd = dd0; fbk = t;
                if (dd1 < fbd) { fbd = dd1; fbk = t + 256; }
            }
#pragma unroll
            for (int mm = 1; mm < 64; mm <<= 1) {
                const float ob = __shfl_xor(fbd, mm, 64);
                const int   ok = __shfl_xor(fbk, mm, 64);
                if (ob < fbd || (ob == fbd && ok < fbk)) { fbd = ob; fbk = ok; }
            }
            if (l == 0) { wredD[w] = fbd; wredK[w] = fbk; }
            __syncthreads();
            if (t == 0) {
                float fb = wredD[0]; int fk = wredK[0];
#pragma unroll
                for (int i = 1; i < 4; ++i) {
                    if (wredD[i] < fb || (wredD[i] == fb && wredK[i] < fk)) {
                        fb = wredD[i]; fk = wredK[i];
                    }
                }
                idx_s[row] = fk;
            }
            __syncthreads();
        }
    }

    // ---- epilogue: gather code, write q_st (NCHW coalesced), loss.
    const int p  = t & 127;
    const int d0 = (t >> 7) * 32;
    const int myidx = idx_s[p];
    const float* qrow = cb + (size_t)myidx * 64 + d0;
    float* oB = out + (size_t)b * (Dz * HWz) + s0 + p;
    float lsum = 0.f;
#pragma unroll
    for (int j = 0; j < 8; ++j) {
        const int d = d0 + 4 * j;
        const float4 q4 = *(const float4*)(qrow + 4 * j);
        const float y0 = zT[(d + 0) * PSTR + p];
        const float y1 = zT[(d + 1) * PSTR + p];
        const float y2 = zT[(d + 2) * PSTR + p];
        const float y3 = zT[(d + 3) * PSTR + p];
        const float e0 = y0 - q4.x, e1 = y1 - q4.y;
        const float e2 = y2 - q4.z, e3 = y3 - q4.w;
        lsum += e0 * e0; lsum += e1 * e1; lsum += e2 * e2; lsum += e3 * e3;
        oB[(size_t)(d + 0) * HWz] = y0 + (q4.x - y0);
        oB[(size_t)(d + 1) * HWz] = y1 + (q4.y - y1);
        oB[(size_t)(d + 2) * HWz] = y2 + (q4.z - y2);
        oB[(size_t)(d + 3) * HWz] = y3 + (q4.w - y3);
    }
#pragma unroll
    for (int off = 32; off > 0; off >>= 1) lsum += __shfl_down(lsum, off, 64);
    if (l == 0) wsum[w] = lsum;
    __syncthreads();
    if (t == 0) {
        float tot = (wsum[0] + wsum[1]) + (wsum[2] + wsum[3]);
        atomicAdd(loss_accum, tot);
        __threadfence();
        unsigned int ticket = atomicAdd(done_counter, 1u);
        if (ticket == gridDim.x - 1) {
            __threadfence();
            float total = atomicAdd(loss_accum, 0.0f);
            float X = total / (float)QSIZE;
            out[QSIZE] = X + 0.25f * X;
        }
    }
}

extern "C" void kernel_launch(void* const* d_in, const int* in_sizes, int n_in,
                              void* d_out, int out_size, void* d_ws, size_t ws_size,
                              hipStream_t stream) {
    const float* z  = (const float*)d_in[0];
    const float* cb = (const float*)d_in[1];
    float* out = (float*)d_out;
    // ws layout: [0:8) loss+done, [64:64+147456) split cb, then cnorm[512].
    float* lossp = (float*)d_ws;
    unsigned int* donep = (unsigned int*)((char*)d_ws + 4);
    unsigned short* cbws = (unsigned short*)((char*)d_ws + 64);
    float* cnws = (float*)((char*)d_ws + 64 + 8 * BUFU * 2);
    vq_prep<<<32, 256, 0, stream>>>(cb, cbws, cnws, lossp, donep);
    vq_main<<<Nz / 128, 256, 0, stream>>>(z, cb, cbws, cnws, out, lossp, donep);
}